// Round 3
// baseline (658.062 us; speedup 1.0000x reference)
//
#include <hip/hip_runtime.h>
#include <cstdint>
#include <cstddef>

#define HD   1024
#define SEQL 200
#define MEMN 50
#define RTOT 51200   // 256 * 200
#define KP   128
#define PADK 136     // KP + 8 bf16 pad -> LDS row stride 272B (2-way, free)

typedef float  f4    __attribute__((ext_vector_type(4)));
typedef float  f32x4 __attribute__((ext_vector_type(4)));
typedef short  s16x8 __attribute__((ext_vector_type(8)));
typedef unsigned short u16;
typedef unsigned short u16x4 __attribute__((ext_vector_type(4)));

__device__ __forceinline__ u16 f2bf(float f) {
    unsigned u = __builtin_bit_cast(unsigned, f);
    u += 0x7FFFu + ((u >> 16) & 1u);          // RNE
    return (u16)(u >> 16);
}
__device__ __forceinline__ float bf2f(u16 h) {
    unsigned u = ((unsigned)h) << 16;
    return __builtin_bit_cast(float, u);
}

#define GLOAD_LDS16(g, l) __builtin_amdgcn_global_load_lds( \
    (const __attribute__((address_space(1))) unsigned int*)(g), \
    (__attribute__((address_space(3))) unsigned int*)(l), 16, 0, 0)

// ---------------------------------------------------------------------------
// K0a: gate_w f32 -> bf16 (layout preserved: [o][2048], K-contiguous)
// ---------------------------------------------------------------------------
__global__ __launch_bounds__(256) void k_cvt_w(const float* __restrict__ gw,
                                               u16* __restrict__ gwB)
{
    const size_t i = ((size_t)blockIdx.x * 256 + threadIdx.x) * 8;
    f4 v0 = *(const f4*)&gw[i];
    f4 v1 = *(const f4*)&gw[i + 4];
    u16x4 b0 = { f2bf(v0.x), f2bf(v0.y), f2bf(v0.z), f2bf(v0.w) };
    u16x4 b1 = { f2bf(v1.x), f2bf(v1.y), f2bf(v1.z), f2bf(v1.w) };
    *(u16x4*)&gwB[i]     = b0;
    *(u16x4*)&gwB[i + 4] = b1;
}

// ---------------------------------------------------------------------------
// K0b: spatial memory -> {memHi, memLo} [64][1024] bf16 (rows 50..63 zero)
//      and memT [1024][64] bf16 (hi only, transposed, zero-padded).
// ---------------------------------------------------------------------------
__global__ __launch_bounds__(256) void k_prep_mem(const float* __restrict__ sm,
                                                  u16* __restrict__ memHi,
                                                  u16* __restrict__ memLo,
                                                  u16* __restrict__ memT)
{
    const int idx = blockIdx.x * 256 + threadIdx.x;   // 16384 total
    const int m  = idx >> 8;
    const int h0 = (idx & 255) * 4;
    f4 v = {0.f, 0.f, 0.f, 0.f};
    if (m < MEMN) v = *(const f4*)&sm[(size_t)m * HD + h0];
    u16x4 hi = { f2bf(v.x), f2bf(v.y), f2bf(v.z), f2bf(v.w) };
    f4 hv = { bf2f(hi.x), bf2f(hi.y), bf2f(hi.z), bf2f(hi.w) };
    f4 lv = v - hv;
    u16x4 lo = { f2bf(lv.x), f2bf(lv.y), f2bf(lv.z), f2bf(lv.w) };
    *(u16x4*)&memHi[(size_t)m * HD + h0] = hi;
    *(u16x4*)&memLo[(size_t)m * HD + h0] = lo;
    memT[(size_t)(h0 + 0) * 64 + m] = hi.x;
    memT[(size_t)(h0 + 1) * 64 + m] = hi.y;
    memT[(size_t)(h0 + 2) * 64 + m] = hi.z;
    memT[(size_t)(h0 + 3) * 64 + m] = hi.w;
}

// ---------------------------------------------------------------------------
// K1: feats = x + pos (store bf16); sim via bf16x2-split MFMA; softmax;
//     mem_read via MFMA (store bf16). 64 rows/block, 4 waves.
// ---------------------------------------------------------------------------
__global__ __launch_bounds__(256) void k_pre(
    const float* __restrict__ x, const float* __restrict__ pos,
    const u16* __restrict__ memHi, const u16* __restrict__ memLo,
    const u16* __restrict__ memT,
    u16* __restrict__ featsB, u16* __restrict__ memrB)
{
    __shared__ u16 fHi[64 * PADK];
    __shared__ u16 fLo[64 * PADK];
    __shared__ u16 wB[64 * 72];      // softmax weights bf16, row stride 144B

    const int tid  = threadIdx.x;
    const int r0   = blockIdx.x * 64;
    const int lane = tid & 63, w = tid >> 6;
    const int fr   = lane & 15;           // MFMA frag row/col within tile
    const int fk   = (lane >> 4) * 8;     // MFMA frag k offset
    const int jr   = (lane >> 4) * 4;     // C-frag row base

    const int srow = tid >> 2;            // staging row 0..63 (== wave's rows)
    const int scol = (tid & 3) * 4;
    const int prow = (r0 + srow) % SEQL;

    f32x4 acc[4] = {};                    // sim[16 rows][m = n*16 + fr]

    for (int kp = 0; kp < HD; kp += KP) {
        // ---- stage feats hi/lo into LDS, emit bf16 feats to global ----
        #pragma unroll
        for (int i = 0; i < 8; ++i) {
            const int c = scol + i * 16;
            f4 xv = *(const f4*)&x[(size_t)(r0 + srow) * HD + kp + c];
            f4 pv = *(const f4*)&pos[(size_t)prow * HD + kp + c];
            f4 fv = xv + pv;
            u16x4 hi = { f2bf(fv.x), f2bf(fv.y), f2bf(fv.z), f2bf(fv.w) };
            f4 hv = { bf2f(hi.x), bf2f(hi.y), bf2f(hi.z), bf2f(hi.w) };
            f4 lv = fv - hv;
            u16x4 lo = { f2bf(lv.x), f2bf(lv.y), f2bf(lv.z), f2bf(lv.w) };
            *(u16x4*)&fHi[srow * PADK + c] = hi;
            *(u16x4*)&fLo[srow * PADK + c] = lo;
            *(u16x4*)&featsB[(size_t)(r0 + srow) * HD + kp + c] = hi;
        }
        __syncthreads();

        // ---- sim MFMA: 3 split-passes, B-frags straight from L2 ----
        #pragma unroll
        for (int ks = 0; ks < KP / 32; ++ks) {
            const int kb = ks * 32 + fk;
            s16x8 aH = *(const s16x8*)&fHi[(16 * w + fr) * PADK + kb];
            s16x8 aL = *(const s16x8*)&fLo[(16 * w + fr) * PADK + kb];
            #pragma unroll
            for (int n = 0; n < 4; ++n) {
                const size_t mb = (size_t)(n * 16 + fr) * HD + kp + kb;
                s16x8 bH = *(const s16x8*)&memHi[mb];
                s16x8 bL = *(const s16x8*)&memLo[mb];
                acc[n] = __builtin_amdgcn_mfma_f32_16x16x32_bf16(aH, bH, acc[n], 0, 0, 0);
                acc[n] = __builtin_amdgcn_mfma_f32_16x16x32_bf16(aH, bL, acc[n], 0, 0, 0);
                acc[n] = __builtin_amdgcn_mfma_f32_16x16x32_bf16(aL, bH, acc[n], 0, 0, 0);
            }
        }
        __syncthreads();
    }

    // ---- softmax over m (50) in f32 ----
    #pragma unroll
    for (int j = 0; j < 4; ++j) {
        float v[4];
        float mx = -1e30f;
        #pragma unroll
        for (int n = 0; n < 4; ++n) {
            v[n] = acc[n][j];
            const int m = n * 16 + fr;
            if (m < MEMN) mx = fmaxf(mx, v[n]);
        }
        #pragma unroll
        for (int d = 1; d < 16; d <<= 1) mx = fmaxf(mx, __shfl_xor(mx, d));
        float e[4], s = 0.f;
        #pragma unroll
        for (int n = 0; n < 4; ++n) {
            const int m = n * 16 + fr;
            e[n] = (m < MEMN) ? __expf(v[n] - mx) : 0.f;
            s += e[n];
        }
        #pragma unroll
        for (int d = 1; d < 16; d <<= 1) s += __shfl_xor(s, d);
        const float inv = 1.f / s;
        const int rloc = 16 * w + jr + j;
        #pragma unroll
        for (int n = 0; n < 4; ++n)
            wB[rloc * 72 + n * 16 + fr] = f2bf(e[n] * inv);   // 0 for m>=50
    }

    // ---- mem_read = w @ mem via MFMA (K = 64, zero-padded) ----
    s16x8 aW[2];
    #pragma unroll
    for (int ks = 0; ks < 2; ++ks)
        aW[ks] = *(const s16x8*)&wB[(16 * w + fr) * 72 + ks * 32 + fk];

    for (int c0 = 0; c0 < HD; c0 += 128) {
        f32x4 a2[8] = {};
        #pragma unroll
        for (int ks = 0; ks < 2; ++ks) {
            #pragma unroll
            for (int nt = 0; nt < 8; ++nt) {
                const int h = c0 + nt * 16 + fr;
                s16x8 bT = *(const s16x8*)&memT[(size_t)h * 64 + ks * 32 + fk];
                a2[nt] = __builtin_amdgcn_mfma_f32_16x16x32_bf16(aW[ks], bT, a2[nt], 0, 0, 0);
            }
        }
        #pragma unroll
        for (int nt = 0; nt < 8; ++nt) {
            const int h = c0 + nt * 16 + fr;
            #pragma unroll
            for (int j = 0; j < 4; ++j) {
                const int r = r0 + 16 * w + jr + j;
                memrB[(size_t)r * HD + h] = f2bf(a2[nt][j]);
            }
        }
    }
}

// ---------------------------------------------------------------------------
// K2: gate GEMM (M=51200, N=1024, K=2048 concat) + sigmoid + residual out.
//     BM=256, BN=128, BK=64, 8 waves (4Mx2N), 512 threads.
//     3 LDS K-tile buffers, prefetch distance 2, counted vmcnt(12),
//     XOR-swizzled LDS (pre-swizzled global source + swizzled ds_read).
// ---------------------------------------------------------------------------
__global__ __launch_bounds__(512, 2) void k_gate_out(
    const u16* __restrict__ featsB, const u16* __restrict__ memrB,
    const u16* __restrict__ gwB, const float* __restrict__ gb,
    float* __restrict__ out)
{
    __shared__ u16 As[3][256 * 64];   // 96 KB
    __shared__ u16 Bs[3][128 * 64];   // 48 KB

    const int tid = threadIdx.x;
    int bid = blockIdx.x;
    bid = (bid & 7) * 200 + (bid >> 3);      // XCD swizzle (1600 % 8 == 0)
    const int mt = bid >> 3, nt = bid & 7;
    const int row0 = mt * 256, col0 = nt * 128;
    const int lane = tid & 63, w = tid >> 6;   // 8 waves
    const int wm = w >> 1, wn = w & 1;         // 4M x 2N
    const int fr = lane & 15, sg = lane >> 4;  // frag row / 16B slot group

    f32x4 acc[4][4] = {};

    // staging lane geometry (per global_load_lds instr: 8 rows x 128B)
    const int lr = lane >> 3;        // row within 8-row chunk
    const int lp = lane & 7;         // phys 16B slot

    auto stage = [&](int buf, int kt) {
        const u16* Asrc = (kt < 16) ? featsB : memrB;
        const int k0 = (kt & 15) * 64;
        #pragma unroll
        for (int i = 0; i < 4; ++i) {                 // A: rows w*32 .. +31
            const int rbase = w * 32 + i * 8;
            const int r = rbase + lr;
            const int c = lp ^ (r & 7);               // pre-swizzled source
            GLOAD_LDS16(Asrc + (size_t)(row0 + r) * HD + k0 + c * 8,
                        &As[buf][rbase * 64]);
        }
        #pragma unroll
        for (int i = 0; i < 2; ++i) {                 // B: rows w*16 .. +15
            const int rbase = w * 16 + i * 8;
            const int r = rbase + lr;
            const int c = lp ^ (r & 7);
            GLOAD_LDS16(gwB + (size_t)(col0 + r) * 2048 + kt * 64 + c * 8,
                        &Bs[buf][rbase * 64]);
        }
    };

    stage(0, 0); stage(1, 1); stage(2, 2);            // prologue: 3 tiles deep

    for (int kt = 0; kt < 32; ++kt) {
        const int buf = kt % 3;
        if (kt < 30)       asm volatile("s_waitcnt vmcnt(12)" ::: "memory");
        else if (kt == 30) asm volatile("s_waitcnt vmcnt(6)"  ::: "memory");
        else               asm volatile("s_waitcnt vmcnt(0)"  ::: "memory");
        __builtin_amdgcn_s_barrier();
        __builtin_amdgcn_sched_barrier(0);

        s16x8 aF[2][4], bF[2][4];
        #pragma unroll
        for (int ks = 0; ks < 2; ++ks) {
            #pragma unroll
            for (int m = 0; m < 4; ++m) {
                const int r = wm * 64 + m * 16 + fr;
                const int s = (ks * 4 + sg) ^ (r & 7);
                aF[ks][m] = *(const s16x8*)&As[buf][r * 64 + s * 8];
            }
            #pragma unroll
            for (int n = 0; n < 4; ++n) {
                const int r = wn * 64 + n * 16 + fr;
                const int s = (ks * 4 + sg) ^ (r & 7);
                bF[ks][n] = *(const s16x8*)&Bs[buf][r * 64 + s * 8];
            }
        }

        __builtin_amdgcn_s_setprio(1);
        #pragma unroll
        for (int ks = 0; ks < 2; ++ks)
            #pragma unroll
            for (int m = 0; m < 4; ++m)
                #pragma unroll
                for (int n = 0; n < 4; ++n)
                    acc[m][n] = __builtin_amdgcn_mfma_f32_16x16x32_bf16(
                        aF[ks][m], bF[ks][n], acc[m][n], 0, 0, 0);
        __builtin_amdgcn_s_setprio(0);

        __builtin_amdgcn_sched_barrier(0);
        __builtin_amdgcn_s_barrier();                 // all waves done reading buf
        if (kt + 3 < 32) stage(buf, kt + 3);          // overwrite now legal
    }

    // epilogue: out = feats + sigmoid(acc + b) * mem_read
    #pragma unroll
    for (int m = 0; m < 4; ++m) {
        #pragma unroll
        for (int n = 0; n < 4; ++n) {
            const int crow = row0 + wm * 64 + m * 16 + (lane >> 4) * 4;
            const int ccol = col0 + wn * 64 + n * 16 + fr;
            const float bias = gb[ccol];
            #pragma unroll
            for (int j = 0; j < 4; ++j) {
                const size_t idx = (size_t)(crow + j) * HD + ccol;
                const float fe = bf2f(featsB[idx]);
                const float mr = bf2f(memrB[idx]);
                const float pre = acc[m][n][j] + bias;
                const float g = 1.0f / (1.0f + __expf(-pre));
                out[idx] = fe + g * mr;
            }
        }
    }
}

// ---------------------------------------------------------------------------
extern "C" void kernel_launch(void* const* d_in, const int* in_sizes, int n_in,
                              void* d_out, int out_size, void* d_ws, size_t ws_size,
                              hipStream_t stream)
{
    const float* x   = (const float*)d_in[0];
    const float* sm  = (const float*)d_in[1];
    const float* pos = (const float*)d_in[2];
    const float* gw  = (const float*)d_in[3];
    const float* gb  = (const float*)d_in[4];
    float* out = (float*)d_out;

    u16* featsB = (u16*)d_ws;                          // 51200*1024
    u16* memrB  = featsB + (size_t)RTOT * HD;          // 51200*1024
    u16* gwB    = memrB + (size_t)RTOT * HD;           // 1024*2048
    u16* memHi  = gwB + (size_t)HD * 2048;             // 64*1024
    u16* memLo  = memHi + 64 * HD;                     // 64*1024
    u16* memT   = memLo + 64 * HD;                     // 1024*64

    k_cvt_w<<<dim3(1024), dim3(256), 0, stream>>>(gw, gwB);
    k_prep_mem<<<dim3(64), dim3(256), 0, stream>>>(sm, memHi, memLo, memT);
    k_pre<<<dim3(RTOT / 64), dim3(256), 0, stream>>>(x, pos, memHi, memLo, memT,
                                                     featsB, memrB);
    k_gate_out<<<dim3(1600), dim3(512), 0, stream>>>(featsB, memrB, gwB, gb, out);
}